// Round 10
// baseline (264.183 us; speedup 1.0000x reference)
//
#include <hip/hip_runtime.h>
#include <stdint.h>

// WaveNetX forward. B=64, L=2048, V=30, E=128, G=8, C=64, F=128, O=30, K=2, ND=9.
// R21: R20 + layer 8 fused into the head (final8_k): stage res7 tile+halo(-512),
//      layer_k GEMM1/gate/GEMM2 body -> skip8, then s = relu(res7+skip8-res0)
//      feeds final_k's W1/W2 body directly. Kills resC round-trip (33.6 MB
//      ~ 24 us at the observed ~1.4 TB/s cache-system throughput) + 1 dispatch.
//      Cost model (R20 post-mortem): layer passes are cache-traffic-bound;
//      the lever is eliminating res trips, not per-dispatch micro-structure.
//      Chain: fused(0-4) A->B, pair(5,6) B->C, layer(7) C->B, final8(A,B)->out.
#define Bz 64
#define Lz 2048
#define Vz 30
#define Ez 128
#define Gz 8
#define Cz 64
#define Fz 128
#define Oz 30
#define NDz 9

#define TWOLOG2E 2.8853900817779268f
#define NLOG2E  -1.4426950408889634f

typedef __attribute__((ext_vector_type(8))) short short8;       // 8 bf16
typedef _Float16 half8 __attribute__((ext_vector_type(8)));     // 8 fp16 = 4 VGPR (MFMA)
typedef __fp16 fp16x2 __attribute__((ext_vector_type(2)));      // cvt_pkrtz result
typedef __attribute__((ext_vector_type(4))) float floatx4;      // 16x16 C/D

#define MFMA16B __builtin_amdgcn_mfma_f32_16x16x32_bf16
#define MFMA16H __builtin_amdgcn_mfma_f32_16x16x32_f16

__device__ __forceinline__ uint16_t f2bf(float f) {             // RNE f32->bf16
    uint32_t u = __float_as_uint(f);
    u += 0x7fffu + ((u >> 16) & 1u);
    return (uint16_t)(u >> 16);
}
__device__ __forceinline__ uint16_t f2h(float f) {              // RNE f32->fp16
    return __builtin_bit_cast(uint16_t, (_Float16)f);
}
__device__ __forceinline__ uint32_t pk2h(float lo, float hi) {  // 1 inst pack
    fp16x2 h = __builtin_amdgcn_cvt_pkrtz(lo, hi);
    return __builtin_bit_cast(uint32_t, h);
}
__device__ __forceinline__ uint32_t pkadd(uint32_t oldbits, float a, float b) {
    fp16x2 h = __builtin_bit_cast(fp16x2, oldbits) + __builtin_amdgcn_cvt_pkrtz(a, b);
    return __builtin_bit_cast(uint32_t, h);
}
__device__ __forceinline__ float h2f(uint32_t u16bits) {        // low 16 bits
    return (float)__builtin_bit_cast(_Float16, (uint16_t)u16bits);
}
__device__ __forceinline__ float fexp2(float x) {               // v_exp_f32 (2^x)
#if __has_builtin(__builtin_amdgcn_exp2f)
    return __builtin_amdgcn_exp2f(x);
#else
    float r; asm("v_exp_f32 %0, %1" : "=v"(r) : "v"(x)); return r;
#endif
}
// tanh(f)*sigmoid(g) with exp2-folded inputs: fl = 2*log2e*f, gl = -log2e*g
// (scaling folded into weights+bias at pack time).
__device__ __forceinline__ float gatefn(float fl, float gl) {
    float a = fexp2(fl);           // = exp(2f)
    float b = fexp2(gl);           // = exp(-g)
    float ap1 = a + 1.f;
    return (a - 1.f) * __builtin_amdgcn_rcpf(fmaf(ap1, b, ap1));
}

// section sizes for pack_k
#define N_WB   (NDz * 128 * 128)   // 147456
#define N_WR   (NDz * 64 * 64)     // 36864
#define N_W1   (Fz * Cz)           // 8192
#define N_W2   (32 * Fz)           // 4096
#define N_PROJ (Vz * Cz)           // 1920
#define N_WLB  (NDz * 128 * 1024)  // 1179648
#define N_EMB  (Bz * 1024)         // 65536
#define N_BIAS (NDz * 128)         // 1152

// ---------------------------------------------------------------------------
// Pack weights (layer/head fp16; conditioning GEMM bf16) + proj + embG + bias.
// Gate-feeding sections (WB, WLB, biasrow) carry the exp2 folding scales.
// ---------------------------------------------------------------------------
__global__ void pack_k(const float* __restrict__ w_f, const float* __restrict__ w_g,
                       const float* __restrict__ w_res, const float* __restrict__ w_fin1,
                       const float* __restrict__ w_fin2, const float* __restrict__ w_causal,
                       const float* __restrict__ table, const int* __restrict__ gin,
                       const float* __restrict__ wl_f, const float* __restrict__ wl_g,
                       const float* __restrict__ b_f, const float* __restrict__ b_g,
                       const float* __restrict__ bl_f, const float* __restrict__ bl_g,
                       uint16_t* __restrict__ WB, uint16_t* __restrict__ WrB,
                       uint16_t* __restrict__ W1B, uint16_t* __restrict__ W2B,
                       float* __restrict__ proj0, float* __restrict__ proj1,
                       uint16_t* __restrict__ WLB, uint16_t* __restrict__ embG,
                       float* __restrict__ biasrow) {
    int tid = blockIdx.x * 256 + threadIdx.x;
    if (tid < N_WB) {
        int i = tid >> 14, rem = tid & 16383, ch = rem >> 7, k = rem & 127;
        int kin = k & 63, tap = (k < 64) ? 1 : 0;
        float v = (ch < 64) ? w_f[((i * Cz + ch) * Cz + kin) * 2 + tap] * TWOLOG2E
                            : w_g[((i * Cz + (ch - 64)) * Cz + kin) * 2 + tap] * NLOG2E;
        WB[tid] = f2h(v);
        return;
    }
    tid -= N_WB;
    if (tid < N_WR) { WrB[tid] = f2h(w_res[tid]); return; }
    tid -= N_WR;
    if (tid < N_W1) { W1B[tid] = f2h(w_fin1[tid]); return; }
    tid -= N_W1;
    if (tid < N_W2) {
        int o = tid >> 7, f = tid & 127;
        W2B[tid] = f2h(o < Oz ? w_fin2[o * Fz + f] : 0.f);
        return;
    }
    tid -= N_W2;
    if (tid < N_PROJ) {
        int v = tid >> 6, c = tid & 63;
        float s0 = 0.f, s1 = 0.f;
        if (v != 0) {
            for (int e = 0; e < Ez; e++) {
                float tv = table[v * Ez + e];
                s0 += w_causal[(c * Ez + e) * 2 + 0] * tv;
                s1 += w_causal[(c * Ez + e) * 2 + 1] * tv;
            }
        }
        proj0[tid] = s0; proj1[tid] = s1;
        return;
    }
    tid -= N_PROJ;
    if (tid < N_WLB) {
        int row = tid >> 10, j = tid & 1023;
        int i = row >> 7, rem = row & 127, fg = rem >> 6, c = rem & 63;
        const float* wl = fg ? wl_g : wl_f;
        float sc = fg ? NLOG2E : TWOLOG2E;
        WLB[tid] = f2bf(wl[((size_t)(i * Cz + c)) * 1024 + j] * sc);
        return;
    }
    tid -= N_WLB;
    if (tid < N_EMB) {
        int b = tid >> 10, j = tid & 1023;
        int g = j >> 7, e = j & 127;
        int v = gin[b * Gz + g];
        embG[tid] = f2bf(v ? table[v * Ez + e] : 0.f);
        return;
    }
    tid -= N_EMB;
    if (tid < N_BIAS) {
        int i = tid >> 7, rem = tid & 127, fg = rem >> 6, c = rem & 63;
        float bsum = (fg ? b_g : b_f)[i * Cz + c] + (fg ? bl_g : bl_f)[i * Cz + c];
        biasrow[tid] = bsum * (fg ? NLOG2E : TWOLOG2E);
    }
}

// ---------------------------------------------------------------------------
// hhT[row(1152)][b(64)] = biasrow[row] + WLB[row,:] . embG[b,:]   (bf16 MFMA)
// 72 blocks x 16 rows; 4 waves split K (8 ks each); LDS reduce.
// ---------------------------------------------------------------------------
__global__ __launch_bounds__(256) void hgemm_k(
    const uint16_t* __restrict__ WLB, const uint16_t* __restrict__ embG,
    const float* __restrict__ biasrow, float* __restrict__ hhT) {
    __shared__ float red[4][4][64][4];   // [nt][wave][lane][r] = 16 KB
    int tx = threadIdx.x, lane = tx & 63, wave = tx >> 6;
    int nl = lane & 15, quad = lane >> 4;
    int row0 = blockIdx.x * 16;
    floatx4 acc[4];
#pragma unroll
    for (int nt = 0; nt < 4; nt++)
#pragma unroll
        for (int r = 0; r < 4; r++) acc[nt][r] = 0.f;
    const uint16_t* ap = WLB + (size_t)(row0 + nl) * 1024 + quad * 8;
#pragma unroll
    for (int k8 = 0; k8 < 8; k8++) {
        int ks = wave * 8 + k8;
        short8 a = *(const short8*)(ap + ks * 32);
#pragma unroll
        for (int nt = 0; nt < 4; nt++) {
            short8 bb = *(const short8*)(embG + (size_t)(nt * 16 + nl) * 1024 + ks * 32 + quad * 8);
            acc[nt] = MFMA16B(a, bb, acc[nt], 0, 0, 0);
        }
    }
#pragma unroll
    for (int nt = 0; nt < 4; nt++)
#pragma unroll
        for (int r = 0; r < 4; r++) red[nt][wave][lane][r] = acc[nt][r];
    __syncthreads();
    {
        int nt = wave;                       // wave w reduces + writes nt = w
#pragma unroll
        for (int r = 0; r < 4; r++) {
            float s = red[nt][0][lane][r] + red[nt][1][lane][r] +
                      red[nt][2][lane][r] + red[nt][3][lane][r];
            hhT[(size_t)(row0 + quad * 4 + r) * 64 + nt * 16 + nl] =
                s + biasrow[row0 + quad * 4 + r];
        }
    }
}

// ---------------------------------------------------------------------------
// Initial conv as token lookup; res layout [b][t][c], fp16.
// ---------------------------------------------------------------------------
__global__ __launch_bounds__(256) void init_k(
    const int* __restrict__ tok, const float* __restrict__ b_causal,
    const float* __restrict__ proj0, const float* __restrict__ proj1,
    uint16_t* __restrict__ res) {
    int tx = threadIdx.x;
    int q = tx & 15, tl = tx >> 4;
    int b = blockIdx.y;
    int t = blockIdx.x * 16 + tl;
    int v1 = tok[b * Lz + t];
    int v0 = (t > 0) ? tok[b * Lz + t - 1] : 0;   // proj0 row 0 is zero
    float4 p1 = ((const float4*)(proj1 + v1 * Cz))[q];
    float4 p0 = ((const float4*)(proj0 + v0 * Cz))[q];
    float4 bc = ((const float4*)b_causal)[q];
    float rx = p1.x + p0.x + bc.x, ry = p1.y + p0.y + bc.y;
    float rz = p1.z + p0.z + bc.z, rw = p1.w + p0.w + bc.w;
    *(uint2*)(res + ((size_t)(b * Lz + t)) * Cz + q * 4) =
        make_uint2(pk2h(rx, ry), pk2h(rz, rw));
}

// ---------------------------------------------------------------------------
// FUSED layers 0..4 (d = 2..32). 128-pos tile + 64-row halo = 192 rows.
// R fp16 [192][72]; Zb fp16 [192][64] XOR-swizzled (elem ^ ((row&7)<<3)).
// LDS 52,224 B -> 3 blocks/CU = 12 waves. (unchanged from R17, ~64 us)
// ---------------------------------------------------------------------------
__global__ __launch_bounds__(256, 3) void fused_k(
    const uint16_t* __restrict__ rin, uint16_t* __restrict__ rout,
    const uint16_t* __restrict__ WB, const uint16_t* __restrict__ WrB,
    const float* __restrict__ hhT, const float* __restrict__ b_res) {
    __shared__ __align__(16) uint16_t R[192 * 72];   // res fp16 [s][ch], stride 72
    __shared__ __align__(16) uint16_t Zb[192 * 64];  // gated z, stride 64, swizzled
    int tx = threadIdx.x;
    int lane = tx & 63, wave = tx >> 6;
    int nl = lane & 15, quad = lane >> 4;
    int b = blockIdx.y, t0 = blockIdx.x * 128;
    const uint16_t* rb16 = rin + ((size_t)b * Lz) * Cz;

    // ---- stage 192 rows (raw fp16 copy): s <-> t = t0-64+s ----
    if (t0 != 0) {
        const uint16_t* src = rb16 + (size_t)(t0 - 64) * Cz;
#pragma unroll
        for (int it = 0; it < 6; it++) {
            int id = it * 256 + tx, row = id >> 3, c8 = id & 7;
            uint4 v = *(const uint4*)(src + (size_t)row * Cz + c8 * 8);
            *(uint4*)(R + row * 72 + c8 * 8) = v;
        }
    } else {
#pragma unroll
        for (int it = 0; it < 6; it++) {
            int id = it * 256 + tx, row = id >> 3, c8 = id & 7;
            int t = row - 64;
            uint4 v = make_uint4(0u, 0u, 0u, 0u);
            if (t >= 0) v = *(const uint4*)(rb16 + (size_t)t * Cz + c8 * 8);
            *(uint4*)(R + row * 72 + c8 * 8) = v;
        }
    }
    floatx4 ss[8];
#pragma unroll
    for (int j = 0; j < 8; j++)
#pragma unroll
        for (int r = 0; r < 4; r++) ss[j][r] = 0.f;
    __syncthreads();

    const int chq = wave * 16 + quad * 4;
    const int zmask = (nl & 7) << 3;            // thread-constant swizzle
    const int zwr  = chq ^ zmask;               // Zb write elem offset
    const int zrd0 = (quad * 8) ^ zmask;        // Zb read elem offsets
    const int zrd1 = (quad * 8 + 32) ^ zmask;
    const int NT0[5] = {0, 0, 1, 2, 4};

#pragma unroll
    for (int l = 0; l < 5; l++) {
        const int d = 2 << l;
        const int nt0 = NT0[l];
        const uint16_t* wf = WB + l * 16384 + (wave * 16 + nl) * 128 + quad * 8;
        half8 AF[4], AG[4];
#pragma unroll
        for (int ks = 0; ks < 4; ks++) {
            AF[ks] = *(const half8*)(wf + ks * 32);
            AG[ks] = *(const half8*)(wf + 64 * 128 + ks * 32);
        }
        const uint16_t* wr = WrB + l * 4096 + (wave * 16 + nl) * 64 + quad * 8;
        half8 AR0 = *(const half8*)(wr);
        half8 AR1 = *(const half8*)(wr + 32);
        float hfv[4], hgv[4], brv[4];
        const float* hp = hhT + ((size_t)(l * 128 + wave * 16 + quad * 4)) * 64 + b;
#pragma unroll
        for (int r = 0; r < 4; r++) { hfv[r] = hp[r * 64]; hgv[r] = hp[4096 + r * 64]; }
        const float* brp = b_res + l * Cz + wave * 16 + quad * 4;
#pragma unroll
        for (int r = 0; r < 4; r++) brv[r] = brp[r];

        // ---- GEMM1 + gate -> Zb (swizzled) ----
#pragma unroll
        for (int nt = 0; nt < 12; nt++) {
            if (nt < nt0) continue;
            int rowa = nt * 16 + nl;
            int rowb = rowa - d;
            if (nt * 16 < d) rowb = rowb < 0 ? 0 : rowb;   // only l=0/1, nt=0;
                                                           // rows 0..3 are don't-care
            const uint16_t* ra = R + rowa * 72 + quad * 8;
            const uint16_t* rb = R + rowb * 72 + quad * 8;
            half8 b0 = *(const half8*)(ra);
            half8 b1 = *(const half8*)(ra + 32);
            half8 b2 = *(const half8*)(rb);
            half8 b3 = *(const half8*)(rb + 32);
            floatx4 aF, aG;
#pragma unroll
            for (int r = 0; r < 4; r++) { aF[r] = hfv[r]; aG[r] = hgv[r]; }
            aF = MFMA16H(AF[0], b0, aF, 0, 0, 0); aG = MFMA16H(AG[0], b0, aG, 0, 0, 0);
            aF = MFMA16H(AF[1], b1, aF, 0, 0, 0); aG = MFMA16H(AG[1], b1, aG, 0, 0, 0);
            aF = MFMA16H(AF[2], b2, aF, 0, 0, 0); aG = MFMA16H(AG[2], b2, aG, 0, 0, 0);
            aF = MFMA16H(AF[3], b3, aF, 0, 0, 0); aG = MFMA16H(AG[3], b3, aG, 0, 0, 0);
            float z0 = gatefn(aF[0], aG[0]);
            float z1 = gatefn(aF[1], aG[1]);
            float z2 = gatefn(aF[2], aG[2]);
            float z3 = gatefn(aF[3], aG[3]);
            *(uint2*)(Zb + rowa * 64 + zwr) = make_uint2(pk2h(z0, z1), pk2h(z2, z3));
        }
        __syncthreads();

        // ---- GEMM2 + in-place R update (v_pk_add_f16) + fp32 skip accum ----
        if (t0 != 0) {
#pragma unroll
            for (int nt = 0; nt < 12; nt++) {
                if (nt < nt0) continue;
                int pos = nt * 16 + nl;
                const uint16_t* zb0 = Zb + pos * 64;
                floatx4 a2;
#pragma unroll
                for (int r = 0; r < 4; r++) a2[r] = brv[r];
                a2 = MFMA16H(AR0, *(const half8*)(zb0 + zrd0), a2, 0, 0, 0);
                a2 = MFMA16H(AR1, *(const half8*)(zb0 + zrd1), a2, 0, 0, 0);
                uint16_t* rp = R + pos * 72 + chq;
                uint2 oldp = *(uint2*)rp;
                *(uint2*)rp = make_uint2(pkadd(oldp.x, a2[0], a2[1]),
                                         pkadd(oldp.y, a2[2], a2[3]));
                if (nt >= 4) {
#pragma unroll
                    for (int r = 0; r < 4; r++) ss[nt - 4][r] += a2[r];
                }
            }
        } else {
#pragma unroll
            for (int nt = 0; nt < 12; nt++) {
                if (nt < nt0) continue;
                int pos = nt * 16 + nl;
                const uint16_t* zb0 = Zb + pos * 64;
                floatx4 a2;
#pragma unroll
                for (int r = 0; r < 4; r++) a2[r] = brv[r];
                a2 = MFMA16H(AR0, *(const half8*)(zb0 + zrd0), a2, 0, 0, 0);
                a2 = MFMA16H(AR1, *(const half8*)(zb0 + zrd1), a2, 0, 0, 0);
                bool ok = (pos >= 64);                      // t = t0-64+pos >= 0
                uint16_t* rp = R + pos * 72 + chq;
                uint2 oldp = *(uint2*)rp;
                uint32_t ux = ok ? pkadd(oldp.x, a2[0], a2[1]) : 0u;
                uint32_t uy = ok ? pkadd(oldp.y, a2[2], a2[3]) : 0u;
                *(uint2*)rp = make_uint2(ux, uy);
                if (nt >= 4) {
#pragma unroll
                    for (int r = 0; r < 4; r++) ss[nt - 4][r] += a2[r];
                }
            }
        }
        __syncthreads();
    }

    // ---- epilogue: rout = fp16(rin + sum(skips)), tile rows only ----
    uint16_t* ro = rout + ((size_t)b * Lz) * Cz;
#pragma unroll
    for (int j = 0; j < 8; j++) {
        size_t off = (size_t)(t0 + j * 16 + nl) * Cz + chq;
        uint2 rv = *(const uint2*)(rb16 + off);
        *(uint2*)(ro + off) = make_uint2(pkadd(rv.x, ss[j][0], ss[j][1]),
                                         pkadd(rv.y, ss[j][2], ss[j][3]));
    }
}

// ---------------------------------------------------------------------------
// PAIR layers 5+6 (d = 64, 128). 128-pos tile + 192-row halo = 320 rows.
// R fp16 [320][72]; layer 5 updates rows 64..319, layer 6 rows 192..319;
// Zb rows indexed s-64 (256 rows), XOR-swizzled. No ss[] — residual lives in
// R; epilogue copies rows 192..319 out. LDS 78,848 B -> 2 blocks/CU.
// (unchanged from R20, ~64 us)
// ---------------------------------------------------------------------------
__global__ __launch_bounds__(256, 2) void pair_k(
    const uint16_t* __restrict__ rin, uint16_t* __restrict__ rout,
    const uint16_t* __restrict__ WB, const uint16_t* __restrict__ WrB,
    const float* __restrict__ hhT, const float* __restrict__ b_res) {
    __shared__ __align__(16) uint16_t R[320 * 72];   // 46,080 B
    __shared__ __align__(16) uint16_t Zb[256 * 64];  // 32,768 B, swizzled
    int tx = threadIdx.x;
    int lane = tx & 63, wave = tx >> 6;
    int nl = lane & 15, quad = lane >> 4;
    int b = blockIdx.y, t0 = blockIdx.x * 128;
    const uint16_t* rb16 = rin + ((size_t)b * Lz) * Cz;

    // ---- stage 320 rows: s <-> t = t0-192+s ----
    if (t0 >= 192) {
        const uint16_t* src = rb16 + (size_t)(t0 - 192) * Cz;
#pragma unroll
        for (int it = 0; it < 10; it++) {
            int id = it * 256 + tx, row = id >> 3, c8 = id & 7;
            uint4 v = *(const uint4*)(src + (size_t)row * Cz + c8 * 8);
            *(uint4*)(R + row * 72 + c8 * 8) = v;
        }
    } else {
#pragma unroll
        for (int it = 0; it < 10; it++) {
            int id = it * 256 + tx, row = id >> 3, c8 = id & 7;
            int t = t0 - 192 + row;
            uint4 v = make_uint4(0u, 0u, 0u, 0u);
            if (t >= 0) v = *(const uint4*)(rb16 + (size_t)t * Cz + c8 * 8);
            *(uint4*)(R + row * 72 + c8 * 8) = v;
        }
    }
    __syncthreads();

    const int chq = wave * 16 + quad * 4;
    const int zmask = (nl & 7) << 3;
    const int zwr  = chq ^ zmask;
    const int zrd0 = (quad * 8) ^ zmask;
    const int zrd1 = (quad * 8 + 32) ^ zmask;
    const int thr = 192 - t0;                   // rows s >= thr are valid (t>=0)

#pragma unroll
    for (int li = 0; li < 2; li++) {
        const int l = 5 + li;
        const int d = 64 << li;                 // 64, 128
        const int ntLo = li ? 12 : 4;           // group range [ntLo, 20)
        const uint16_t* wf = WB + l * 16384 + (wave * 16 + nl) * 128 + quad * 8;
        half8 AF[4], AG[4];
#pragma unroll
        for (int ks = 0; ks < 4; ks++) {
            AF[ks] = *(const half8*)(wf + ks * 32);
            AG[ks] = *(const half8*)(wf + 64 * 128 + ks * 32);
        }
        const uint16_t* wr = WrB + l * 4096 + (wave * 16 + nl) * 64 + quad * 8;
        half8 AR0 = *(const half8*)(wr);
        half8 AR1 = *(const half8*)(wr + 32);
        float hfv[4], hgv[4], brv[4];
        const float* hp = hhT + ((size_t)(l * 128 + wave * 16 + quad * 4)) * 64 + b;
#pragma unroll
        for (int r = 0; r < 4; r++) { hfv[r] = hp[r * 64]; hgv[r] = hp[4096 + r * 64]; }
        const float* brp = b_res + l * Cz + wave * 16 + quad * 4;
#pragma unroll
        for (int r = 0; r < 4; r++) brv[r] = brp[r];

        // ---- GEMM1 + gate -> Zb (row index s-64, swizzled) ----
#pragma unroll
        for (int nt = ntLo; nt < 20; nt++) {
            if (li == 0 && nt * 16 < thr) continue;        // wave-uniform skip
            int rowa = nt * 16 + nl;
            int rowb = rowa - d;                           // >= 0 always here
            const uint16_t* ra = R + rowa * 72 + quad * 8;
            const uint16_t* rb = R + rowb * 72 + quad * 8;
            half8 b0 = *(const half8*)(ra);
            half8 b1 = *(const half8*)(ra + 32);
            half8 b2 = *(const half8*)(rb);
            half8 b3 = *(const half8*)(rb + 32);
            floatx4 aF, aG;
#pragma unroll
            for (int r = 0; r < 4; r++) { aF[r] = hfv[r]; aG[r] = hgv[r]; }
            aF = MFMA16H(AF[0], b0, aF, 0, 0, 0); aG = MFMA16H(AG[0], b0, aG, 0, 0, 0);
            aF = MFMA16H(AF[1], b1, aF, 0, 0, 0); aG = MFMA16H(AG[1], b1, aG, 0, 0, 0);
            aF = MFMA16H(AF[2], b2, aF, 0, 0, 0); aG = MFMA16H(AG[2], b2, aG, 0, 0, 0);
            aF = MFMA16H(AF[3], b3, aF, 0, 0, 0); aG = MFMA16H(AG[3], b3, aG, 0, 0, 0);
            float z0 = gatefn(aF[0], aG[0]);
            float z1 = gatefn(aF[1], aG[1]);
            float z2 = gatefn(aF[2], aG[2]);
            float z3 = gatefn(aF[3], aG[3]);
            *(uint2*)(Zb + (rowa - 64) * 64 + zwr) = make_uint2(pk2h(z0, z1), pk2h(z2, z3));
        }
        __syncthreads();

        // ---- GEMM2 + in-place R update ----
#pragma unroll
        for (int nt = ntLo; nt < 20; nt++) {
            if (li == 0 && nt * 16 < thr) continue;        // keep invalid rows zero
            int pos = nt * 16 + nl;
            const uint16_t* zb0 = Zb + (pos - 64) * 64;
            floatx4 a2;
#pragma unroll
            for (int r = 0; r < 4; r++) a2[r] = brv[r];
            a2 = MFMA16H(AR0, *(const half8*)(zb0 + zrd0), a2, 0, 0, 0);
            a2 = MFMA16H(AR1, *(const half8*)(zb0 + zrd1), a2, 0, 0, 0);
            uint16_t* rp = R + pos * 72 + chq;
            uint2 oldp = *(uint2*)rp;
            *(uint2*)rp = make_uint2(pkadd(oldp.x, a2[0], a2[1]),
                                     pkadd(oldp.y, a2[2], a2[3]));
        }
        __syncthreads();
    }

    // ---- epilogue: rout[t0 + j] = R[192 + j] (straight copy) ----
    uint16_t* ro = rout + ((size_t)b * Lz) * Cz;
#pragma unroll
    for (int j = 0; j < 8; j++) {
        int s = 192 + j * 16 + nl;
        size_t off = (size_t)(t0 + j * 16 + nl) * Cz + chq;
        *(uint2*)(ro + off) = *(const uint2*)(R + s * 72 + chq);
    }
}

// ---------------------------------------------------------------------------
// One layer (d >= 128). Block = 64 positions x 1 batch, 4 waves. fp16 in/out.
// R17 form exactly (best measured): X staging, (256,4).
// ---------------------------------------------------------------------------
__global__ __launch_bounds__(256, 4) void layer_k(
    const uint16_t* __restrict__ rin, uint16_t* __restrict__ rout,
    const uint16_t* __restrict__ WBl, const uint16_t* __restrict__ WrBl,
    const float* __restrict__ hhT, const float* __restrict__ b_res,
    int i, int d) {
    __shared__ __align__(16) uint16_t X[64 * 136];   // [pos][k128] pad->136
    __shared__ __align__(16) uint16_t Z[64 * 72];    // [pos][c64]  pad->72
    int tx = threadIdx.x;
    int lane = tx & 63, wave = tx >> 6;
    int nl = lane & 15, quad = lane >> 4;
    int b = blockIdx.y, t0 = blockIdx.x * 64;
    const uint16_t* rb16 = rin + ((size_t)b * Lz) * Cz;

#pragma unroll
    for (int it = 0; it < 2; it++) {
        int id = it * 256 + tx, row = id >> 3, c8 = id & 7;
        uint4 v = *(const uint4*)(rb16 + (size_t)(t0 + row) * Cz + c8 * 8);
        *(uint4*)(X + row * 136 + c8 * 8) = v;
    }
#pragma unroll
    for (int it = 0; it < 2; it++) {
        int id = it * 256 + tx, row = id >> 3, c8 = id & 7;
        int tb = t0 + row - d;
        uint4 v = make_uint4(0u, 0u, 0u, 0u);
        if (tb >= 0) v = *(const uint4*)(rb16 + (size_t)tb * Cz + c8 * 8);
        *(uint4*)(X + row * 136 + 64 + c8 * 8) = v;
    }

    half8 AF[4], AG[4], AR[2];
    {
        const uint16_t* wf = WBl + (wave * 16 + nl) * 128 + quad * 8;
#pragma unroll
        for (int ks = 0; ks < 4; ks++) {
            AF[ks] = *(const half8*)(wf + ks * 32);
            AG[ks] = *(const half8*)(wf + 64 * 128 + ks * 32);
        }
        const uint16_t* wr = WrBl + (wave * 16 + nl) * 64 + quad * 8;
#pragma unroll
        for (int ks = 0; ks < 2; ks++) AR[ks] = *(const half8*)(wr + ks * 32);
    }
    float hfv[4], hgv[4], brv[4];
    {
        const float* hp = hhT + ((size_t)(i * 128 + wave * 16 + quad * 4)) * 64 + b;
#pragma unroll
        for (int r = 0; r < 4; r++) {
            hfv[r] = hp[r * 64];
            hgv[r] = hp[4096 + r * 64];
        }
        const float* brp = b_res + i * Cz + wave * 16 + quad * 4;
#pragma unroll
        for (int r = 0; r < 4; r++) brv[r] = brp[r];
    }
    __syncthreads();

    floatx4 accF[4], accG[4];
#pragma unroll
    for (int nt = 0; nt < 4; nt++)
#pragma unroll
        for (int r = 0; r < 4; r++) { accF[nt][r] = hfv[r]; accG[nt][r] = hgv[r]; }
#pragma unroll
    for (int nt = 0; nt < 4; nt++) {
        const uint16_t* xp = X + (nt * 16 + nl) * 136 + quad * 8;
#pragma unroll
        for (int ks = 0; ks < 4; ks++) {
            half8 bf = *(const half8*)(xp + ks * 32);
            accF[nt] = MFMA16H(AF[ks], bf, accF[nt], 0, 0, 0);
            accG[nt] = MFMA16H(AG[ks], bf, accG[nt], 0, 0, 0);
        }
    }

    int chq = wave * 16 + quad * 4;
#pragma unroll
    for (int nt = 0; nt < 4; nt++) {
        int pos = nt * 16 + nl;
        float z0 = gatefn(accF[nt][0], accG[nt][0]);
        float z1 = gatefn(accF[nt][1], accG[nt][1]);
        float z2 = gatefn(accF[nt][2], accG[nt][2]);
        float z3 = gatefn(accF[nt][3], accG[nt][3]);
        *(uint2*)(Z + pos * 72 + chq) = make_uint2(pk2h(z0, z1), pk2h(z2, z3));
    }
    __syncthreads();

    floatx4 acc2[4];
#pragma unroll
    for (int nt = 0; nt < 4; nt++)
#pragma unroll
        for (int r = 0; r < 4; r++) acc2[nt][r] = brv[r];
#pragma unroll
    for (int nt = 0; nt < 4; nt++) {
        const uint16_t* zp = Z + (nt * 16 + nl) * 72 + quad * 8;
        acc2[nt] = MFMA16H(AR[0], *(const half8*)zp, acc2[nt], 0, 0, 0);
        acc2[nt] = MFMA16H(AR[1], *(const half8*)(zp + 32), acc2[nt], 0, 0, 0);
    }

    uint16_t* ro = rout + ((size_t)b * Lz) * Cz;
#pragma unroll
    for (int nt = 0; nt < 4; nt++) {
        size_t off = (size_t)(t0 + nt * 16 + nl) * Cz + chq;
        uint2 rv = *(const uint2*)(rb16 + off);
        *(uint2*)(ro + off) = make_uint2(pkadd(rv.x, acc2[nt][0], acc2[nt][1]),
                                         pkadd(rv.y, acc2[nt][2], acc2[nt][3]));
    }
}

// ---------------------------------------------------------------------------
// final8_k: layer 8 (d=512) + head fused. 64-pos tile.
// Phase A (layer_k body): stage X = res7 tile + halo(-512); GEMM1+gate -> Z;
// GEMM2 -> skip8. Phase B: S = relu(res7 + skip8 - res0) (res7 from X,
// res0 one global read). Phase C/D (final_k body): W1 -> relu -> Mi; W2 -> out.
// LDS 17,408 + 9,216 + 9,216 + 17,408 = 53,248 B -> 3 blocks/CU.
// Kills the res8 global round-trip (33.6 MB) + one dispatch.
// ---------------------------------------------------------------------------
__global__ __launch_bounds__(256, 3) void final8_k(
    const uint16_t* __restrict__ res0, const uint16_t* __restrict__ res7,
    const uint16_t* __restrict__ WBl, const uint16_t* __restrict__ WrBl,
    const float* __restrict__ hhT, const float* __restrict__ b_res,
    const uint16_t* __restrict__ W1B, const uint16_t* __restrict__ W2B,
    const float* __restrict__ b_fin1, const float* __restrict__ b_fin2,
    float* __restrict__ out) {
    __shared__ __align__(16) uint16_t X[64 * 136];   // res7 [pos][k128]
    __shared__ __align__(16) uint16_t Z[64 * 72];    // gated z
    __shared__ __align__(16) uint16_t S[64 * 72];    // relu'd skip sum
    __shared__ __align__(16) uint16_t Mi[64 * 136];  // mid (F=128)
    const int d = 512;
    int tx = threadIdx.x;
    int lane = tx & 63, wave = tx >> 6;
    int nl = lane & 15, quad = lane >> 4;
    int b = blockIdx.y, t0 = blockIdx.x * 64;
    const uint16_t* r7 = res7 + ((size_t)b * Lz) * Cz;
    const uint16_t* r0 = res0 + ((size_t)b * Lz) * Cz;

    // ---- stage X = res7 tile + halo ----
#pragma unroll
    for (int it = 0; it < 2; it++) {
        int id = it * 256 + tx, row = id >> 3, c8 = id & 7;
        uint4 v = *(const uint4*)(r7 + (size_t)(t0 + row) * Cz + c8 * 8);
        *(uint4*)(X + row * 136 + c8 * 8) = v;
    }
#pragma unroll
    for (int it = 0; it < 2; it++) {
        int id = it * 256 + tx, row = id >> 3, c8 = id & 7;
        int tb = t0 + row - d;
        uint4 v = make_uint4(0u, 0u, 0u, 0u);
        if (tb >= 0) v = *(const uint4*)(r7 + (size_t)tb * Cz + c8 * 8);
        *(uint4*)(X + row * 136 + 64 + c8 * 8) = v;
    }

    half8 AF[4], AG[4], AR[2];
    {
        const uint16_t* wf = WBl + (wave * 16 + nl) * 128 + quad * 8;
#pragma unroll
        for (int ks = 0; ks < 4; ks++) {
            AF[ks] = *(const half8*)(wf + ks * 32);
            AG[ks] = *(const half8*)(wf + 64 * 128 + ks * 32);
        }
        const uint16_t* wr = WrBl + (wave * 16 + nl) * 64 + quad * 8;
#pragma unroll
        for (int ks = 0; ks < 2; ks++) AR[ks] = *(const half8*)(wr + ks * 32);
    }
    float hfv[4], hgv[4], brv[4];
    {
        const float* hp = hhT + ((size_t)(8 * 128 + wave * 16 + quad * 4)) * 64 + b;
#pragma unroll
        for (int r = 0; r < 4; r++) {
            hfv[r] = hp[r * 64];
            hgv[r] = hp[4096 + r * 64];
        }
        const float* brp = b_res + 8 * Cz + wave * 16 + quad * 4;
#pragma unroll
        for (int r = 0; r < 4; r++) brv[r] = brp[r];
    }
    __syncthreads();

    // ---- GEMM1 + gate -> Z ----
    int chq = wave * 16 + quad * 4;
#pragma unroll
    for (int nt = 0; nt < 4; nt++) {
        const uint16_t* xp = X + (nt * 16 + nl) * 136 + quad * 8;
        floatx4 aF, aG;
#pragma unroll
        for (int r = 0; r < 4; r++) { aF[r] = hfv[r]; aG[r] = hgv[r]; }
#pragma unroll
        for (int ks = 0; ks < 4; ks++) {
            half8 bf = *(const half8*)(xp + ks * 32);
            aF = MFMA16H(AF[ks], bf, aF, 0, 0, 0);
            aG = MFMA16H(AG[ks], bf, aG, 0, 0, 0);
        }
        int pos = nt * 16 + nl;
        float z0 = gatefn(aF[0], aG[0]);
        float z1 = gatefn(aF[1], aG[1]);
        float z2 = gatefn(aF[2], aG[2]);
        float z3 = gatefn(aF[3], aG[3]);
        *(uint2*)(Z + pos * 72 + chq) = make_uint2(pk2h(z0, z1), pk2h(z2, z3));
    }
    __syncthreads();

    // ---- GEMM2 -> skip8; S = relu(res7 + skip8 - res0) ----
#pragma unroll
    for (int nt = 0; nt < 4; nt++) {
        int pos = nt * 16 + nl;
        const uint16_t* zp = Z + pos * 72 + quad * 8;
        floatx4 a2;
#pragma unroll
        for (int r = 0; r < 4; r++) a2[r] = brv[r];
        a2 = MFMA16H(AR[0], *(const half8*)zp, a2, 0, 0, 0);
        a2 = MFMA16H(AR[1], *(const half8*)(zp + 32), a2, 0, 0, 0);
        uint2 xv = *(const uint2*)(X + pos * 136 + chq);        // res7(tile)
        uint2 ov = *(const uint2*)(r0 + (size_t)(t0 + pos) * Cz + chq);
        float s0 = fmaxf(h2f(xv.x)       + a2[0] - h2f(ov.x),       0.f);
        float s1 = fmaxf(h2f(xv.x >> 16) + a2[1] - h2f(ov.x >> 16), 0.f);
        float s2 = fmaxf(h2f(xv.y)       + a2[2] - h2f(ov.y),       0.f);
        float s3 = fmaxf(h2f(xv.y >> 16) + a2[3] - h2f(ov.y >> 16), 0.f);
        *(uint2*)(S + pos * 72 + chq) = make_uint2(pk2h(s0, s1), pk2h(s2, s3));
    }
    __syncthreads();

    // ---- W1: mid = relu(W1 s + b1) -> Mi ----
    half8 A1[2][2];
#pragma unroll
    for (int mt = 0; mt < 2; mt++) {
        const uint16_t* w1 = W1B + (wave * 32 + mt * 16 + nl) * 64 + quad * 8;
#pragma unroll
        for (int ks = 0; ks < 2; ks++) A1[mt][ks] = *(const half8*)(w1 + ks * 32);
    }
    floatx4 accM[2][4];
#pragma unroll
    for (int mt = 0; mt < 2; mt++) {
        float b1v[4];
#pragma unroll
        for (int r = 0; r < 4; r++) b1v[r] = b_fin1[wave * 32 + mt * 16 + quad * 4 + r];
#pragma unroll
        for (int nt = 0; nt < 4; nt++)
#pragma unroll
            for (int r = 0; r < 4; r++) accM[mt][nt][r] = b1v[r];
    }
#pragma unroll
    for (int nt = 0; nt < 4; nt++) {
        const uint16_t* sp = S + (nt * 16 + nl) * 72 + quad * 8;
#pragma unroll
        for (int ks = 0; ks < 2; ks++) {
            half8 s = *(const half8*)(sp + ks * 32);
            accM[0][nt] = MFMA16H(A1[0][ks], s, accM[0][nt], 0, 0, 0);
            accM[1][nt] = MFMA16H(A1[1][ks], s, accM[1][nt], 0, 0, 0);
        }
    }
#pragma unroll
    for (int mt = 0; mt < 2; mt++)
#pragma unroll
        for (int nt = 0; nt < 4; nt++) {
            int pos = nt * 16 + nl;
            int fq = wave * 32 + mt * 16 + quad * 4;
            float m0 = fmaxf(accM[mt][nt][0], 0.f), m1 = fmaxf(accM[mt][nt][1], 0.f);
            float m2 = fmaxf(accM[mt][nt][2], 0.f), m3 = fmaxf(accM[mt][nt][3], 0.f);
            *(uint2*)(Mi + pos * 136 + fq) = make_uint2(pk2h(m0, m1), pk2h(m2, m3));
        }
    __syncthreads();

    // ---- W2: out = W2 mid + b2; each wave owns pos-group nt = wave ----
    half8 A2[2][4];
#pragma unroll
    for (int mt = 0; mt < 2; mt++) {
        const uint16_t* w2 = W2B + (mt * 16 + nl) * 128 + quad * 8;
#pragma unroll
        for (int ks = 0; ks < 4; ks++) A2[mt][ks] = *(const half8*)(w2 + ks * 32);
    }
    floatx4 accO[2];
#pragma unroll
    for (int mt = 0; mt < 2; mt++)
#pragma unroll
        for (int r = 0; r < 4; r++) {
            int o = mt * 16 + quad * 4 + r;
            accO[mt][r] = (o < Oz) ? b_fin2[o] : 0.f;
        }
    {
        const uint16_t* mp = Mi + (wave * 16 + nl) * 136 + quad * 8;
#pragma unroll
        for (int ks = 0; ks < 4; ks++) {
            half8 m = *(const half8*)(mp + ks * 32);
            accO[0] = MFMA16H(A2[0][ks], m, accO[0], 0, 0, 0);
            accO[1] = MFMA16H(A2[1][ks], m, accO[1], 0, 0, 0);
        }
    }
#pragma unroll
    for (int mt = 0; mt < 2; mt++)
#pragma unroll
        for (int r = 0; r < 4; r++) {
            int o = mt * 16 + quad * 4 + r;
            if (o < Oz)
                out[((size_t)b * Oz + o) * Lz + t0 + wave * 16 + nl] = accO[mt][r];
        }
}

// ---------------------------------------------------------------------------
extern "C" void kernel_launch(void* const* d_in, const int* in_sizes, int n_in,
                              void* d_out, int out_size, void* d_ws, size_t ws_size,
                              hipStream_t stream) {
    const int*   tok      = (const int*)d_in[0];
    const int*   gin      = (const int*)d_in[1];
    const float* table    = (const float*)d_in[2];
    const float* w_causal = (const float*)d_in[3];
    const float* b_causal = (const float*)d_in[4];
    const float* w_f      = (const float*)d_in[5];
    const float* b_f      = (const float*)d_in[6];
    const float* w_g      = (const float*)d_in[7];
    const float* b_g      = (const float*)d_in[8];
    const float* wl_f     = (const float*)d_in[9];
    const float* bl_f     = (const float*)d_in[10];
    const float* wl_g     = (const float*)d_in[11];
    const float* bl_g     = (const float*)d_in[12];
    const float* w_res    = (const float*)d_in[13];
    const float* b_res    = (const float*)d_in[14];
    const float* w_fin1   = (const float*)d_in[15];
    const float* b_fin1   = (const float*)d_in[16];
    const float* w_fin2   = (const float*)d_in[17];
    const float* b_fin2   = (const float*)d_in[18];
    float* out = (float*)d_out;

    const size_t NRES = (size_t)Bz * Lz * Cz;        // 8388608 elements
    uint16_t* u16 = (uint16_t*)d_ws;
    uint16_t* resA = u16;                             // fp16 trunk buffers
    uint16_t* resB = resA + NRES;
    uint16_t* resC = resB + NRES;
    uint16_t* WB   = resC + NRES;                     // 147456
    uint16_t* WrB  = WB + N_WB;                       // 36864
    uint16_t* W1B  = WrB + N_WR;                      // 8192
    uint16_t* W2B  = W1B + N_W1;                      // 4096
    uint16_t* WLB  = W2B + N_W2;                      // 1179648
    uint16_t* embG = WLB + N_WLB;                     // 65536
    float* hhT     = (float*)(embG + N_EMB);          // 73728 floats
    float* proj0   = hhT + 73728;                     // 1920
    float* proj1   = proj0 + N_PROJ;                  // 1920
    float* biasrow = proj1 + N_PROJ;                  // 1152

    int npack = N_WB + N_WR + N_W1 + N_W2 + N_PROJ + N_WLB + N_EMB + N_BIAS;
    pack_k<<<(npack + 255) / 256, 256, 0, stream>>>(
        w_f, w_g, w_res, w_fin1, w_fin2, w_causal, table, gin,
        wl_f, wl_g, b_f, b_g, bl_f, bl_g,
        WB, WrB, W1B, W2B, proj0, proj1, WLB, embG, biasrow);
    hgemm_k<<<72, 256, 0, stream>>>(WLB, embG, biasrow, hhT);
    init_k<<<dim3(Lz / 16, Bz), 256, 0, stream>>>(tok, b_causal, proj0, proj1, resA);

    // layers 0..4 fused (d = 2..32): resA -> resB
    fused_k<<<dim3(Lz / 128, Bz), 256, 0, stream>>>(resA, resB, WB, WrB, hhT, b_res);
    // layers 5..6 pair-fused (d = 64, 128): resB -> resC
    pair_k<<<dim3(Lz / 128, Bz), 256, 0, stream>>>(resB, resC, WB, WrB, hhT, b_res);
    // layer 7 (d = 256): C -> B
    layer_k<<<dim3(Lz / 64, Bz), 256, 0, stream>>>(
        resC, resB, WB + (size_t)7 * 16384, WrB + (size_t)7 * 4096, hhT, b_res, 7, 256);
    // layer 8 (d = 512) + head fused: reads res0 = resA, res7 = resB
    final8_k<<<dim3(Lz / 64, Bz), 256, 0, stream>>>(
        resA, resB, WB + (size_t)8 * 16384, WrB + (size_t)8 * 4096, hhT, b_res,
        W1B, W2B, b_fin1, b_fin2, out);
}

// Round 11
// 261.910 us; speedup vs baseline: 1.0087x; 1.0087x over previous
//
#include <hip/hip_runtime.h>
#include <stdint.h>

// WaveNetX forward. B=64, L=2048, V=30, E=128, G=8, C=64, F=128, O=30, K=2, ND=9.
// R22: R21 + init_k fused into fused_k's staging: each staged row computes the
//      initial conv inline (tok lookup + proj gather, bit-identical math to
//      init_k) and tile rows are written to resA (still needed as res0 by
//      final8_k). Epilogue re-reads resA (own-block writes, L2-hot,
//      barrier-ordered). Kills the init dispatch + 25 MB of resA reads.
//      NOTE: fused_k WRITE_SIZE ~doubles (resA tile write) — expected, not spill.
//      Chain (6 dispatches): pack -> hgemm -> fused(0-4, init inline) A,B ->
//      pair(5,6) B->C -> layer(7) C->B -> final8(A,B)->out.
#define Bz 64
#define Lz 2048
#define Vz 30
#define Ez 128
#define Gz 8
#define Cz 64
#define Fz 128
#define Oz 30
#define NDz 9

#define TWOLOG2E 2.8853900817779268f
#define NLOG2E  -1.4426950408889634f

typedef __attribute__((ext_vector_type(8))) short short8;       // 8 bf16
typedef _Float16 half8 __attribute__((ext_vector_type(8)));     // 8 fp16 = 4 VGPR (MFMA)
typedef __fp16 fp16x2 __attribute__((ext_vector_type(2)));      // cvt_pkrtz result
typedef __attribute__((ext_vector_type(4))) float floatx4;      // 16x16 C/D

#define MFMA16B __builtin_amdgcn_mfma_f32_16x16x32_bf16
#define MFMA16H __builtin_amdgcn_mfma_f32_16x16x32_f16

__device__ __forceinline__ uint16_t f2bf(float f) {             // RNE f32->bf16
    uint32_t u = __float_as_uint(f);
    u += 0x7fffu + ((u >> 16) & 1u);
    return (uint16_t)(u >> 16);
}
__device__ __forceinline__ uint16_t f2h(float f) {              // RNE f32->fp16
    return __builtin_bit_cast(uint16_t, (_Float16)f);
}
__device__ __forceinline__ uint32_t pk2h(float lo, float hi) {  // 1 inst pack
    fp16x2 h = __builtin_amdgcn_cvt_pkrtz(lo, hi);
    return __builtin_bit_cast(uint32_t, h);
}
__device__ __forceinline__ uint32_t pkadd(uint32_t oldbits, float a, float b) {
    fp16x2 h = __builtin_bit_cast(fp16x2, oldbits) + __builtin_amdgcn_cvt_pkrtz(a, b);
    return __builtin_bit_cast(uint32_t, h);
}
__device__ __forceinline__ float h2f(uint32_t u16bits) {        // low 16 bits
    return (float)__builtin_bit_cast(_Float16, (uint16_t)u16bits);
}
__device__ __forceinline__ float fexp2(float x) {               // v_exp_f32 (2^x)
#if __has_builtin(__builtin_amdgcn_exp2f)
    return __builtin_amdgcn_exp2f(x);
#else
    float r; asm("v_exp_f32 %0, %1" : "=v"(r) : "v"(x)); return r;
#endif
}
// tanh(f)*sigmoid(g) with exp2-folded inputs: fl = 2*log2e*f, gl = -log2e*g
// (scaling folded into weights+bias at pack time).
__device__ __forceinline__ float gatefn(float fl, float gl) {
    float a = fexp2(fl);           // = exp(2f)
    float b = fexp2(gl);           // = exp(-g)
    float ap1 = a + 1.f;
    return (a - 1.f) * __builtin_amdgcn_rcpf(fmaf(ap1, b, ap1));
}

// section sizes for pack_k
#define N_WB   (NDz * 128 * 128)   // 147456
#define N_WR   (NDz * 64 * 64)     // 36864
#define N_W1   (Fz * Cz)           // 8192
#define N_W2   (32 * Fz)           // 4096
#define N_PROJ (Vz * Cz)           // 1920
#define N_WLB  (NDz * 128 * 1024)  // 1179648
#define N_EMB  (Bz * 1024)         // 65536
#define N_BIAS (NDz * 128)         // 1152

// ---------------------------------------------------------------------------
// Pack weights (layer/head fp16; conditioning GEMM bf16) + proj + embG + bias.
// Gate-feeding sections (WB, WLB, biasrow) carry the exp2 folding scales.
// ---------------------------------------------------------------------------
__global__ void pack_k(const float* __restrict__ w_f, const float* __restrict__ w_g,
                       const float* __restrict__ w_res, const float* __restrict__ w_fin1,
                       const float* __restrict__ w_fin2, const float* __restrict__ w_causal,
                       const float* __restrict__ table, const int* __restrict__ gin,
                       const float* __restrict__ wl_f, const float* __restrict__ wl_g,
                       const float* __restrict__ b_f, const float* __restrict__ b_g,
                       const float* __restrict__ bl_f, const float* __restrict__ bl_g,
                       uint16_t* __restrict__ WB, uint16_t* __restrict__ WrB,
                       uint16_t* __restrict__ W1B, uint16_t* __restrict__ W2B,
                       float* __restrict__ proj0, float* __restrict__ proj1,
                       uint16_t* __restrict__ WLB, uint16_t* __restrict__ embG,
                       float* __restrict__ biasrow) {
    int tid = blockIdx.x * 256 + threadIdx.x;
    if (tid < N_WB) {
        int i = tid >> 14, rem = tid & 16383, ch = rem >> 7, k = rem & 127;
        int kin = k & 63, tap = (k < 64) ? 1 : 0;
        float v = (ch < 64) ? w_f[((i * Cz + ch) * Cz + kin) * 2 + tap] * TWOLOG2E
                            : w_g[((i * Cz + (ch - 64)) * Cz + kin) * 2 + tap] * NLOG2E;
        WB[tid] = f2h(v);
        return;
    }
    tid -= N_WB;
    if (tid < N_WR) { WrB[tid] = f2h(w_res[tid]); return; }
    tid -= N_WR;
    if (tid < N_W1) { W1B[tid] = f2h(w_fin1[tid]); return; }
    tid -= N_W1;
    if (tid < N_W2) {
        int o = tid >> 7, f = tid & 127;
        W2B[tid] = f2h(o < Oz ? w_fin2[o * Fz + f] : 0.f);
        return;
    }
    tid -= N_W2;
    if (tid < N_PROJ) {
        int v = tid >> 6, c = tid & 63;
        float s0 = 0.f, s1 = 0.f;
        if (v != 0) {
            for (int e = 0; e < Ez; e++) {
                float tv = table[v * Ez + e];
                s0 += w_causal[(c * Ez + e) * 2 + 0] * tv;
                s1 += w_causal[(c * Ez + e) * 2 + 1] * tv;
            }
        }
        proj0[tid] = s0; proj1[tid] = s1;
        return;
    }
    tid -= N_PROJ;
    if (tid < N_WLB) {
        int row = tid >> 10, j = tid & 1023;
        int i = row >> 7, rem = row & 127, fg = rem >> 6, c = rem & 63;
        const float* wl = fg ? wl_g : wl_f;
        float sc = fg ? NLOG2E : TWOLOG2E;
        WLB[tid] = f2bf(wl[((size_t)(i * Cz + c)) * 1024 + j] * sc);
        return;
    }
    tid -= N_WLB;
    if (tid < N_EMB) {
        int b = tid >> 10, j = tid & 1023;
        int g = j >> 7, e = j & 127;
        int v = gin[b * Gz + g];
        embG[tid] = f2bf(v ? table[v * Ez + e] : 0.f);
        return;
    }
    tid -= N_EMB;
    if (tid < N_BIAS) {
        int i = tid >> 7, rem = tid & 127, fg = rem >> 6, c = rem & 63;
        float bsum = (fg ? b_g : b_f)[i * Cz + c] + (fg ? bl_g : bl_f)[i * Cz + c];
        biasrow[tid] = bsum * (fg ? NLOG2E : TWOLOG2E);
    }
}

// ---------------------------------------------------------------------------
// hhT[row(1152)][b(64)] = biasrow[row] + WLB[row,:] . embG[b,:]   (bf16 MFMA)
// 72 blocks x 16 rows; 4 waves split K (8 ks each); LDS reduce.
// ---------------------------------------------------------------------------
__global__ __launch_bounds__(256) void hgemm_k(
    const uint16_t* __restrict__ WLB, const uint16_t* __restrict__ embG,
    const float* __restrict__ biasrow, float* __restrict__ hhT) {
    __shared__ float red[4][4][64][4];   // [nt][wave][lane][r] = 16 KB
    int tx = threadIdx.x, lane = tx & 63, wave = tx >> 6;
    int nl = lane & 15, quad = lane >> 4;
    int row0 = blockIdx.x * 16;
    floatx4 acc[4];
#pragma unroll
    for (int nt = 0; nt < 4; nt++)
#pragma unroll
        for (int r = 0; r < 4; r++) acc[nt][r] = 0.f;
    const uint16_t* ap = WLB + (size_t)(row0 + nl) * 1024 + quad * 8;
#pragma unroll
    for (int k8 = 0; k8 < 8; k8++) {
        int ks = wave * 8 + k8;
        short8 a = *(const short8*)(ap + ks * 32);
#pragma unroll
        for (int nt = 0; nt < 4; nt++) {
            short8 bb = *(const short8*)(embG + (size_t)(nt * 16 + nl) * 1024 + ks * 32 + quad * 8);
            acc[nt] = MFMA16B(a, bb, acc[nt], 0, 0, 0);
        }
    }
#pragma unroll
    for (int nt = 0; nt < 4; nt++)
#pragma unroll
        for (int r = 0; r < 4; r++) red[nt][wave][lane][r] = acc[nt][r];
    __syncthreads();
    {
        int nt = wave;                       // wave w reduces + writes nt = w
#pragma unroll
        for (int r = 0; r < 4; r++) {
            float s = red[nt][0][lane][r] + red[nt][1][lane][r] +
                      red[nt][2][lane][r] + red[nt][3][lane][r];
            hhT[(size_t)(row0 + quad * 4 + r) * 64 + nt * 16 + nl] =
                s + biasrow[row0 + quad * 4 + r];
        }
    }
}

// ---------------------------------------------------------------------------
// FUSED layers 0..4 (d = 2..32) + inline init. 128-pos tile + 64 halo = 192
// rows. Staging COMPUTES the initial conv (tok lookup + proj gather; math
// bit-identical to the old init_k) and writes tile rows to resA (needed as
// res0 by final8_k). Epilogue reads resA back (own writes, L2-hot, ordered
// by __syncthreads). R fp16 [192][72]; Zb [192][64] XOR-swizzled.
// LDS 52,224 B -> 3 blocks/CU.
// ---------------------------------------------------------------------------
__global__ __launch_bounds__(256, 3) void fused_k(
    const int* __restrict__ tok, const float* __restrict__ b_causal,
    const float* __restrict__ proj0, const float* __restrict__ proj1,
    uint16_t* __restrict__ resA, uint16_t* __restrict__ rout,
    const uint16_t* __restrict__ WB, const uint16_t* __restrict__ WrB,
    const float* __restrict__ hhT, const float* __restrict__ b_res) {
    __shared__ __align__(16) uint16_t R[192 * 72];   // res fp16 [s][ch], stride 72
    __shared__ __align__(16) uint16_t Zb[192 * 64];  // gated z, stride 64, swizzled
    int tx = threadIdx.x;
    int lane = tx & 63, wave = tx >> 6;
    int nl = lane & 15, quad = lane >> 4;
    int b = blockIdx.y, t0 = blockIdx.x * 128;
    uint16_t* ra16 = resA + ((size_t)b * Lz) * Cz;
    const uint16_t* rb16 = ra16;                     // epilogue source

    // ---- stage 192 rows: s <-> t = t0-64+s, computing init conv inline ----
#pragma unroll
    for (int it = 0; it < 6; it++) {
        int id = it * 256 + tx, row = id >> 3, c8 = id & 7;
        int t = t0 - 64 + row;
        uint4 v = make_uint4(0u, 0u, 0u, 0u);
        if (t >= 0) {
            int v1 = tok[b * Lz + t];
            int v0 = (t > 0) ? tok[b * Lz + t - 1] : 0;   // proj0 row 0 is zero
            const float4* P1 = (const float4*)(proj1 + v1 * Cz);
            const float4* P0 = (const float4*)(proj0 + v0 * Cz);
            const float4* BC = (const float4*)b_causal;
            float4 pa = P1[c8 * 2],     qa = P0[c8 * 2],     ca = BC[c8 * 2];
            float4 pb = P1[c8 * 2 + 1], qb = P0[c8 * 2 + 1], cb = BC[c8 * 2 + 1];
            v.x = pk2h(pa.x + qa.x + ca.x, pa.y + qa.y + ca.y);
            v.y = pk2h(pa.z + qa.z + ca.z, pa.w + qa.w + ca.w);
            v.z = pk2h(pb.x + qb.x + cb.x, pb.y + qb.y + cb.y);
            v.w = pk2h(pb.z + qb.z + cb.z, pb.w + qb.w + cb.w);
        }
        *(uint4*)(R + row * 72 + c8 * 8) = v;
        if (row >= 64)                                    // tile rows -> resA
            *(uint4*)(ra16 + (size_t)t * Cz + c8 * 8) = v;
    }
    floatx4 ss[8];
#pragma unroll
    for (int j = 0; j < 8; j++)
#pragma unroll
        for (int r = 0; r < 4; r++) ss[j][r] = 0.f;
    __syncthreads();

    const int chq = wave * 16 + quad * 4;
    const int zmask = (nl & 7) << 3;            // thread-constant swizzle
    const int zwr  = chq ^ zmask;               // Zb write elem offset
    const int zrd0 = (quad * 8) ^ zmask;        // Zb read elem offsets
    const int zrd1 = (quad * 8 + 32) ^ zmask;
    const int NT0[5] = {0, 0, 1, 2, 4};

#pragma unroll
    for (int l = 0; l < 5; l++) {
        const int d = 2 << l;
        const int nt0 = NT0[l];
        const uint16_t* wf = WB + l * 16384 + (wave * 16 + nl) * 128 + quad * 8;
        half8 AF[4], AG[4];
#pragma unroll
        for (int ks = 0; ks < 4; ks++) {
            AF[ks] = *(const half8*)(wf + ks * 32);
            AG[ks] = *(const half8*)(wf + 64 * 128 + ks * 32);
        }
        const uint16_t* wr = WrB + l * 4096 + (wave * 16 + nl) * 64 + quad * 8;
        half8 AR0 = *(const half8*)(wr);
        half8 AR1 = *(const half8*)(wr + 32);
        float hfv[4], hgv[4], brv[4];
        const float* hp = hhT + ((size_t)(l * 128 + wave * 16 + quad * 4)) * 64 + b;
#pragma unroll
        for (int r = 0; r < 4; r++) { hfv[r] = hp[r * 64]; hgv[r] = hp[4096 + r * 64]; }
        const float* brp = b_res + l * Cz + wave * 16 + quad * 4;
#pragma unroll
        for (int r = 0; r < 4; r++) brv[r] = brp[r];

        // ---- GEMM1 + gate -> Zb (swizzled) ----
#pragma unroll
        for (int nt = 0; nt < 12; nt++) {
            if (nt < nt0) continue;
            int rowa = nt * 16 + nl;
            int rowb = rowa - d;
            if (nt * 16 < d) rowb = rowb < 0 ? 0 : rowb;   // only l=0/1, nt=0;
                                                           // rows 0..3 are don't-care
            const uint16_t* ra = R + rowa * 72 + quad * 8;
            const uint16_t* rb = R + rowb * 72 + quad * 8;
            half8 b0 = *(const half8*)(ra);
            half8 b1 = *(const half8*)(ra + 32);
            half8 b2 = *(const half8*)(rb);
            half8 b3 = *(const half8*)(rb + 32);
            floatx4 aF, aG;
#pragma unroll
            for (int r = 0; r < 4; r++) { aF[r] = hfv[r]; aG[r] = hgv[r]; }
            aF = MFMA16H(AF[0], b0, aF, 0, 0, 0); aG = MFMA16H(AG[0], b0, aG, 0, 0, 0);
            aF = MFMA16H(AF[1], b1, aF, 0, 0, 0); aG = MFMA16H(AG[1], b1, aG, 0, 0, 0);
            aF = MFMA16H(AF[2], b2, aF, 0, 0, 0); aG = MFMA16H(AG[2], b2, aG, 0, 0, 0);
            aF = MFMA16H(AF[3], b3, aF, 0, 0, 0); aG = MFMA16H(AG[3], b3, aG, 0, 0, 0);
            float z0 = gatefn(aF[0], aG[0]);
            float z1 = gatefn(aF[1], aG[1]);
            float z2 = gatefn(aF[2], aG[2]);
            float z3 = gatefn(aF[3], aG[3]);
            *(uint2*)(Zb + rowa * 64 + zwr) = make_uint2(pk2h(z0, z1), pk2h(z2, z3));
        }
        __syncthreads();

        // ---- GEMM2 + in-place R update (v_pk_add_f16) + fp32 skip accum ----
        if (t0 != 0) {
#pragma unroll
            for (int nt = 0; nt < 12; nt++) {
                if (nt < nt0) continue;
                int pos = nt * 16 + nl;
                const uint16_t* zb0 = Zb + pos * 64;
                floatx4 a2;
#pragma unroll
                for (int r = 0; r < 4; r++) a2[r] = brv[r];
                a2 = MFMA16H(AR0, *(const half8*)(zb0 + zrd0), a2, 0, 0, 0);
                a2 = MFMA16H(AR1, *(const half8*)(zb0 + zrd1), a2, 0, 0, 0);
                uint16_t* rp = R + pos * 72 + chq;
                uint2 oldp = *(uint2*)rp;
                *(uint2*)rp = make_uint2(pkadd(oldp.x, a2[0], a2[1]),
                                         pkadd(oldp.y, a2[2], a2[3]));
                if (nt >= 4) {
#pragma unroll
                    for (int r = 0; r < 4; r++) ss[nt - 4][r] += a2[r];
                }
            }
        } else {
#pragma unroll
            for (int nt = 0; nt < 12; nt++) {
                if (nt < nt0) continue;
                int pos = nt * 16 + nl;
                const uint16_t* zb0 = Zb + pos * 64;
                floatx4 a2;
#pragma unroll
                for (int r = 0; r < 4; r++) a2[r] = brv[r];
                a2 = MFMA16H(AR0, *(const half8*)(zb0 + zrd0), a2, 0, 0, 0);
                a2 = MFMA16H(AR1, *(const half8*)(zb0 + zrd1), a2, 0, 0, 0);
                bool ok = (pos >= 64);                      // t = t0-64+pos >= 0
                uint16_t* rp = R + pos * 72 + chq;
                uint2 oldp = *(uint2*)rp;
                uint32_t ux = ok ? pkadd(oldp.x, a2[0], a2[1]) : 0u;
                uint32_t uy = ok ? pkadd(oldp.y, a2[2], a2[3]) : 0u;
                *(uint2*)rp = make_uint2(ux, uy);
                if (nt >= 4) {
#pragma unroll
                    for (int r = 0; r < 4; r++) ss[nt - 4][r] += a2[r];
                }
            }
        }
        __syncthreads();
    }

    // ---- epilogue: rout = fp16(resA + sum(skips)), tile rows only ----
    uint16_t* ro = rout + ((size_t)b * Lz) * Cz;
#pragma unroll
    for (int j = 0; j < 8; j++) {
        size_t off = (size_t)(t0 + j * 16 + nl) * Cz + chq;
        uint2 rv = *(const uint2*)(rb16 + off);
        *(uint2*)(ro + off) = make_uint2(pkadd(rv.x, ss[j][0], ss[j][1]),
                                         pkadd(rv.y, ss[j][2], ss[j][3]));
    }
}

// ---------------------------------------------------------------------------
// PAIR layers 5+6 (d = 64, 128). 128-pos tile + 192-row halo = 320 rows.
// R fp16 [320][72]; layer 5 updates rows 64..319, layer 6 rows 192..319;
// Zb rows indexed s-64 (256 rows), XOR-swizzled. No ss[] — residual lives in
// R; epilogue copies rows 192..319 out. LDS 78,848 B -> 2 blocks/CU.
// ---------------------------------------------------------------------------
__global__ __launch_bounds__(256, 2) void pair_k(
    const uint16_t* __restrict__ rin, uint16_t* __restrict__ rout,
    const uint16_t* __restrict__ WB, const uint16_t* __restrict__ WrB,
    const float* __restrict__ hhT, const float* __restrict__ b_res) {
    __shared__ __align__(16) uint16_t R[320 * 72];   // 46,080 B
    __shared__ __align__(16) uint16_t Zb[256 * 64];  // 32,768 B, swizzled
    int tx = threadIdx.x;
    int lane = tx & 63, wave = tx >> 6;
    int nl = lane & 15, quad = lane >> 4;
    int b = blockIdx.y, t0 = blockIdx.x * 128;
    const uint16_t* rb16 = rin + ((size_t)b * Lz) * Cz;

    // ---- stage 320 rows: s <-> t = t0-192+s ----
    if (t0 >= 192) {
        const uint16_t* src = rb16 + (size_t)(t0 - 192) * Cz;
#pragma unroll
        for (int it = 0; it < 10; it++) {
            int id = it * 256 + tx, row = id >> 3, c8 = id & 7;
            uint4 v = *(const uint4*)(src + (size_t)row * Cz + c8 * 8);
            *(uint4*)(R + row * 72 + c8 * 8) = v;
        }
    } else {
#pragma unroll
        for (int it = 0; it < 10; it++) {
            int id = it * 256 + tx, row = id >> 3, c8 = id & 7;
            int t = t0 - 192 + row;
            uint4 v = make_uint4(0u, 0u, 0u, 0u);
            if (t >= 0) v = *(const uint4*)(rb16 + (size_t)t * Cz + c8 * 8);
            *(uint4*)(R + row * 72 + c8 * 8) = v;
        }
    }
    __syncthreads();

    const int chq = wave * 16 + quad * 4;
    const int zmask = (nl & 7) << 3;
    const int zwr  = chq ^ zmask;
    const int zrd0 = (quad * 8) ^ zmask;
    const int zrd1 = (quad * 8 + 32) ^ zmask;
    const int thr = 192 - t0;                   // rows s >= thr are valid (t>=0)

#pragma unroll
    for (int li = 0; li < 2; li++) {
        const int l = 5 + li;
        const int d = 64 << li;                 // 64, 128
        const int ntLo = li ? 12 : 4;           // group range [ntLo, 20)
        const uint16_t* wf = WB + l * 16384 + (wave * 16 + nl) * 128 + quad * 8;
        half8 AF[4], AG[4];
#pragma unroll
        for (int ks = 0; ks < 4; ks++) {
            AF[ks] = *(const half8*)(wf + ks * 32);
            AG[ks] = *(const half8*)(wf + 64 * 128 + ks * 32);
        }
        const uint16_t* wr = WrB + l * 4096 + (wave * 16 + nl) * 64 + quad * 8;
        half8 AR0 = *(const half8*)(wr);
        half8 AR1 = *(const half8*)(wr + 32);
        float hfv[4], hgv[4], brv[4];
        const float* hp = hhT + ((size_t)(l * 128 + wave * 16 + quad * 4)) * 64 + b;
#pragma unroll
        for (int r = 0; r < 4; r++) { hfv[r] = hp[r * 64]; hgv[r] = hp[4096 + r * 64]; }
        const float* brp = b_res + l * Cz + wave * 16 + quad * 4;
#pragma unroll
        for (int r = 0; r < 4; r++) brv[r] = brp[r];

        // ---- GEMM1 + gate -> Zb (row index s-64, swizzled) ----
#pragma unroll
        for (int nt = ntLo; nt < 20; nt++) {
            if (li == 0 && nt * 16 < thr) continue;        // wave-uniform skip
            int rowa = nt * 16 + nl;
            int rowb = rowa - d;                           // >= 0 always here
            const uint16_t* ra = R + rowa * 72 + quad * 8;
            const uint16_t* rb = R + rowb * 72 + quad * 8;
            half8 b0 = *(const half8*)(ra);
            half8 b1 = *(const half8*)(ra + 32);
            half8 b2 = *(const half8*)(rb);
            half8 b3 = *(const half8*)(rb + 32);
            floatx4 aF, aG;
#pragma unroll
            for (int r = 0; r < 4; r++) { aF[r] = hfv[r]; aG[r] = hgv[r]; }
            aF = MFMA16H(AF[0], b0, aF, 0, 0, 0); aG = MFMA16H(AG[0], b0, aG, 0, 0, 0);
            aF = MFMA16H(AF[1], b1, aF, 0, 0, 0); aG = MFMA16H(AG[1], b1, aG, 0, 0, 0);
            aF = MFMA16H(AF[2], b2, aF, 0, 0, 0); aG = MFMA16H(AG[2], b2, aG, 0, 0, 0);
            aF = MFMA16H(AF[3], b3, aF, 0, 0, 0); aG = MFMA16H(AG[3], b3, aG, 0, 0, 0);
            float z0 = gatefn(aF[0], aG[0]);
            float z1 = gatefn(aF[1], aG[1]);
            float z2 = gatefn(aF[2], aG[2]);
            float z3 = gatefn(aF[3], aG[3]);
            *(uint2*)(Zb + (rowa - 64) * 64 + zwr) = make_uint2(pk2h(z0, z1), pk2h(z2, z3));
        }
        __syncthreads();

        // ---- GEMM2 + in-place R update ----
#pragma unroll
        for (int nt = ntLo; nt < 20; nt++) {
            if (li == 0 && nt * 16 < thr) continue;        // keep invalid rows zero
            int pos = nt * 16 + nl;
            const uint16_t* zb0 = Zb + (pos - 64) * 64;
            floatx4 a2;
#pragma unroll
            for (int r = 0; r < 4; r++) a2[r] = brv[r];
            a2 = MFMA16H(AR0, *(const half8*)(zb0 + zrd0), a2, 0, 0, 0);
            a2 = MFMA16H(AR1, *(const half8*)(zb0 + zrd1), a2, 0, 0, 0);
            uint16_t* rp = R + pos * 72 + chq;
            uint2 oldp = *(uint2*)rp;
            *(uint2*)rp = make_uint2(pkadd(oldp.x, a2[0], a2[1]),
                                     pkadd(oldp.y, a2[2], a2[3]));
        }
        __syncthreads();
    }

    // ---- epilogue: rout[t0 + j] = R[192 + j] (straight copy) ----
    uint16_t* ro = rout + ((size_t)b * Lz) * Cz;
#pragma unroll
    for (int j = 0; j < 8; j++) {
        int s = 192 + j * 16 + nl;
        size_t off = (size_t)(t0 + j * 16 + nl) * Cz + chq;
        *(uint2*)(ro + off) = *(const uint2*)(R + s * 72 + chq);
    }
}

// ---------------------------------------------------------------------------
// One layer (d >= 128). Block = 64 positions x 1 batch, 4 waves. fp16 in/out.
// R17 form exactly (best measured): X staging, (256,4).
// ---------------------------------------------------------------------------
__global__ __launch_bounds__(256, 4) void layer_k(
    const uint16_t* __restrict__ rin, uint16_t* __restrict__ rout,
    const uint16_t* __restrict__ WBl, const uint16_t* __restrict__ WrBl,
    const float* __restrict__ hhT, const float* __restrict__ b_res,
    int i, int d) {
    __shared__ __align__(16) uint16_t X[64 * 136];   // [pos][k128] pad->136
    __shared__ __align__(16) uint16_t Z[64 * 72];    // [pos][c64]  pad->72
    int tx = threadIdx.x;
    int lane = tx & 63, wave = tx >> 6;
    int nl = lane & 15, quad = lane >> 4;
    int b = blockIdx.y, t0 = blockIdx.x * 64;
    const uint16_t* rb16 = rin + ((size_t)b * Lz) * Cz;

#pragma unroll
    for (int it = 0; it < 2; it++) {
        int id = it * 256 + tx, row = id >> 3, c8 = id & 7;
        uint4 v = *(const uint4*)(rb16 + (size_t)(t0 + row) * Cz + c8 * 8);
        *(uint4*)(X + row * 136 + c8 * 8) = v;
    }
#pragma unroll
    for (int it = 0; it < 2; it++) {
        int id = it * 256 + tx, row = id >> 3, c8 = id & 7;
        int tb = t0 + row - d;
        uint4 v = make_uint4(0u, 0u, 0u, 0u);
        if (tb >= 0) v = *(const uint4*)(rb16 + (size_t)tb * Cz + c8 * 8);
        *(uint4*)(X + row * 136 + 64 + c8 * 8) = v;
    }

    half8 AF[4], AG[4], AR[2];
    {
        const uint16_t* wf = WBl + (wave * 16 + nl) * 128 + quad * 8;
#pragma unroll
        for (int ks = 0; ks < 4; ks++) {
            AF[ks] = *(const half8*)(wf + ks * 32);
            AG[ks] = *(const half8*)(wf + 64 * 128 + ks * 32);
        }
        const uint16_t* wr = WrBl + (wave * 16 + nl) * 64 + quad * 8;
#pragma unroll
        for (int ks = 0; ks < 2; ks++) AR[ks] = *(const half8*)(wr + ks * 32);
    }
    float hfv[4], hgv[4], brv[4];
    {
        const float* hp = hhT + ((size_t)(i * 128 + wave * 16 + quad * 4)) * 64 + b;
#pragma unroll
        for (int r = 0; r < 4; r++) {
            hfv[r] = hp[r * 64];
            hgv[r] = hp[4096 + r * 64];
        }
        const float* brp = b_res + i * Cz + wave * 16 + quad * 4;
#pragma unroll
        for (int r = 0; r < 4; r++) brv[r] = brp[r];
    }
    __syncthreads();

    floatx4 accF[4], accG[4];
#pragma unroll
    for (int nt = 0; nt < 4; nt++)
#pragma unroll
        for (int r = 0; r < 4; r++) { accF[nt][r] = hfv[r]; accG[nt][r] = hgv[r]; }
#pragma unroll
    for (int nt = 0; nt < 4; nt++) {
        const uint16_t* xp = X + (nt * 16 + nl) * 136 + quad * 8;
#pragma unroll
        for (int ks = 0; ks < 4; ks++) {
            half8 bf = *(const half8*)(xp + ks * 32);
            accF[nt] = MFMA16H(AF[ks], bf, accF[nt], 0, 0, 0);
            accG[nt] = MFMA16H(AG[ks], bf, accG[nt], 0, 0, 0);
        }
    }

    int chq = wave * 16 + quad * 4;
#pragma unroll
    for (int nt = 0; nt < 4; nt++) {
        int pos = nt * 16 + nl;
        float z0 = gatefn(accF[nt][0], accG[nt][0]);
        float z1 = gatefn(accF[nt][1], accG[nt][1]);
        float z2 = gatefn(accF[nt][2], accG[nt][2]);
        float z3 = gatefn(accF[nt][3], accG[nt][3]);
        *(uint2*)(Z + pos * 72 + chq) = make_uint2(pk2h(z0, z1), pk2h(z2, z3));
    }
    __syncthreads();

    floatx4 acc2[4];
#pragma unroll
    for (int nt = 0; nt < 4; nt++)
#pragma unroll
        for (int r = 0; r < 4; r++) acc2[nt][r] = brv[r];
#pragma unroll
    for (int nt = 0; nt < 4; nt++) {
        const uint16_t* zp = Z + (nt * 16 + nl) * 72 + quad * 8;
        acc2[nt] = MFMA16H(AR[0], *(const half8*)zp, acc2[nt], 0, 0, 0);
        acc2[nt] = MFMA16H(AR[1], *(const half8*)(zp + 32), acc2[nt], 0, 0, 0);
    }

    uint16_t* ro = rout + ((size_t)b * Lz) * Cz;
#pragma unroll
    for (int nt = 0; nt < 4; nt++) {
        size_t off = (size_t)(t0 + nt * 16 + nl) * Cz + chq;
        uint2 rv = *(const uint2*)(rb16 + off);
        *(uint2*)(ro + off) = make_uint2(pkadd(rv.x, acc2[nt][0], acc2[nt][1]),
                                         pkadd(rv.y, acc2[nt][2], acc2[nt][3]));
    }
}

// ---------------------------------------------------------------------------
// final8_k: layer 8 (d=512) + head fused. 64-pos tile.
// Phase A (layer_k body): stage X = res7 tile + halo(-512); GEMM1+gate -> Z;
// GEMM2 -> skip8. Phase B: S = relu(res7 + skip8 - res0). Phase C/D
// (final_k body): W1 -> relu -> Mi; W2 -> out. LDS 53,248 B -> 3 blocks/CU.
// ---------------------------------------------------------------------------
__global__ __launch_bounds__(256, 3) void final8_k(
    const uint16_t* __restrict__ res0, const uint16_t* __restrict__ res7,
    const uint16_t* __restrict__ WBl, const uint16_t* __restrict__ WrBl,
    const float* __restrict__ hhT, const float* __restrict__ b_res,
    const uint16_t* __restrict__ W1B, const uint16_t* __restrict__ W2B,
    const float* __restrict__ b_fin1, const float* __restrict__ b_fin2,
    float* __restrict__ out) {
    __shared__ __align__(16) uint16_t X[64 * 136];   // res7 [pos][k128]
    __shared__ __align__(16) uint16_t Z[64 * 72];    // gated z
    __shared__ __align__(16) uint16_t S[64 * 72];    // relu'd skip sum
    __shared__ __align__(16) uint16_t Mi[64 * 136];  // mid (F=128)
    const int d = 512;
    int tx = threadIdx.x;
    int lane = tx & 63, wave = tx >> 6;
    int nl = lane & 15, quad = lane >> 4;
    int b = blockIdx.y, t0 = blockIdx.x * 64;
    const uint16_t* r7 = res7 + ((size_t)b * Lz) * Cz;
    const uint16_t* r0 = res0 + ((size_t)b * Lz) * Cz;

    // ---- stage X = res7 tile + halo ----
#pragma unroll
    for (int it = 0; it < 2; it++) {
        int id = it * 256 + tx, row = id >> 3, c8 = id & 7;
        uint4 v = *(const uint4*)(r7 + (size_t)(t0 + row) * Cz + c8 * 8);
        *(uint4*)(X + row * 136 + c8 * 8) = v;
    }
#pragma unroll
    for (int it = 0; it < 2; it++) {
        int id = it * 256 + tx, row = id >> 3, c8 = id & 7;
        int tb = t0 + row - d;
        uint4 v = make_uint4(0u, 0u, 0u, 0u);
        if (tb >= 0) v = *(const uint4*)(r7 + (size_t)tb * Cz + c8 * 8);
        *(uint4*)(X + row * 136 + 64 + c8 * 8) = v;
    }

    half8 AF[4], AG[4], AR[2];
    {
        const uint16_t* wf = WBl + (wave * 16 + nl) * 128 + quad * 8;
#pragma unroll
        for (int ks = 0; ks < 4; ks++) {
            AF[ks] = *(const half8*)(wf + ks * 32);
            AG[ks] = *(const half8*)(wf + 64 * 128 + ks * 32);
        }
        const uint16_t* wr = WrBl + (wave * 16 + nl) * 64 + quad * 8;
#pragma unroll
        for (int ks = 0; ks < 2; ks++) AR[ks] = *(const half8*)(wr + ks * 32);
    }
    float hfv[4], hgv[4], brv[4];
    {
        const float* hp = hhT + ((size_t)(8 * 128 + wave * 16 + quad * 4)) * 64 + b;
#pragma unroll
        for (int r = 0; r < 4; r++) {
            hfv[r] = hp[r * 64];
            hgv[r] = hp[4096 + r * 64];
        }
        const float* brp = b_res + 8 * Cz + wave * 16 + quad * 4;
#pragma unroll
        for (int r = 0; r < 4; r++) brv[r] = brp[r];
    }
    __syncthreads();

    // ---- GEMM1 + gate -> Z ----
    int chq = wave * 16 + quad * 4;
#pragma unroll
    for (int nt = 0; nt < 4; nt++) {
        const uint16_t* xp = X + (nt * 16 + nl) * 136 + quad * 8;
        floatx4 aF, aG;
#pragma unroll
        for (int r = 0; r < 4; r++) { aF[r] = hfv[r]; aG[r] = hgv[r]; }
#pragma unroll
        for (int ks = 0; ks < 4; ks++) {
            half8 bf = *(const half8*)(xp + ks * 32);
            aF = MFMA16H(AF[ks], bf, aF, 0, 0, 0);
            aG = MFMA16H(AG[ks], bf, aG, 0, 0, 0);
        }
        int pos = nt * 16 + nl;
        float z0 = gatefn(aF[0], aG[0]);
        float z1 = gatefn(aF[1], aG[1]);
        float z2 = gatefn(aF[2], aG[2]);
        float z3 = gatefn(aF[3], aG[3]);
        *(uint2*)(Z + pos * 72 + chq) = make_uint2(pk2h(z0, z1), pk2h(z2, z3));
    }
    __syncthreads();

    // ---- GEMM2 -> skip8; S = relu(res7 + skip8 - res0) ----
#pragma unroll
    for (int nt = 0; nt < 4; nt++) {
        int pos = nt * 16 + nl;
        const uint16_t* zp = Z + pos * 72 + quad * 8;
        floatx4 a2;
#pragma unroll
        for (int r = 0; r < 4; r++) a2[r] = brv[r];
        a2 = MFMA16H(AR[0], *(const half8*)zp, a2, 0, 0, 0);
        a2 = MFMA16H(AR[1], *(const half8*)(zp + 32), a2, 0, 0, 0);
        uint2 xv = *(const uint2*)(X + pos * 136 + chq);        // res7(tile)
        uint2 ov = *(const uint2*)(r0 + (size_t)(t0 + pos) * Cz + chq);
        float s0 = fmaxf(h2f(xv.x)       + a2[0] - h2f(ov.x),       0.f);
        float s1 = fmaxf(h2f(xv.x >> 16) + a2[1] - h2f(ov.x >> 16), 0.f);
        float s2 = fmaxf(h2f(xv.y)       + a2[2] - h2f(ov.y),       0.f);
        float s3 = fmaxf(h2f(xv.y >> 16) + a2[3] - h2f(ov.y >> 16), 0.f);
        *(uint2*)(S + pos * 72 + chq) = make_uint2(pk2h(s0, s1), pk2h(s2, s3));
    }
    __syncthreads();

    // ---- W1: mid = relu(W1 s + b1) -> Mi ----
    half8 A1[2][2];
#pragma unroll
    for (int mt = 0; mt < 2; mt++) {
        const uint16_t* w1 = W1B + (wave * 32 + mt * 16 + nl) * 64 + quad * 8;
#pragma unroll
        for (int ks = 0; ks < 2; ks++) A1[mt][ks] = *(const half8*)(w1 + ks * 32);
    }
    floatx4 accM[2][4];
#pragma unroll
    for (int mt = 0; mt < 2; mt++) {
        float b1v[4];
#pragma unroll
        for (int r = 0; r < 4; r++) b1v[r] = b_fin1[wave * 32 + mt * 16 + quad * 4 + r];
#pragma unroll
        for (int nt = 0; nt < 4; nt++)
#pragma unroll
            for (int r = 0; r < 4; r++) accM[mt][nt][r] = b1v[r];
    }
#pragma unroll
    for (int nt = 0; nt < 4; nt++) {
        const uint16_t* sp = S + (nt * 16 + nl) * 72 + quad * 8;
#pragma unroll
        for (int ks = 0; ks < 2; ks++) {
            half8 s = *(const half8*)(sp + ks * 32);
            accM[0][nt] = MFMA16H(A1[0][ks], s, accM[0][nt], 0, 0, 0);
            accM[1][nt] = MFMA16H(A1[1][ks], s, accM[1][nt], 0, 0, 0);
        }
    }
#pragma unroll
    for (int mt = 0; mt < 2; mt++)
#pragma unroll
        for (int nt = 0; nt < 4; nt++) {
            int pos = nt * 16 + nl;
            int fq = wave * 32 + mt * 16 + quad * 4;
            float m0 = fmaxf(accM[mt][nt][0], 0.f), m1 = fmaxf(accM[mt][nt][1], 0.f);
            float m2 = fmaxf(accM[mt][nt][2], 0.f), m3 = fmaxf(accM[mt][nt][3], 0.f);
            *(uint2*)(Mi + pos * 136 + fq) = make_uint2(pk2h(m0, m1), pk2h(m2, m3));
        }
    __syncthreads();

    // ---- W2: out = W2 mid + b2; each wave owns pos-group nt = wave ----
    half8 A2[2][4];
#pragma unroll
    for (int mt = 0; mt < 2; mt++) {
        const uint16_t* w2 = W2B + (mt * 16 + nl) * 128 + quad * 8;
#pragma unroll
        for (int ks = 0; ks < 4; ks++) A2[mt][ks] = *(const half8*)(w2 + ks * 32);
    }
    floatx4 accO[2];
#pragma unroll
    for (int mt = 0; mt < 2; mt++)
#pragma unroll
        for (int r = 0; r < 4; r++) {
            int o = mt * 16 + quad * 4 + r;
            accO[mt][r] = (o < Oz) ? b_fin2[o] : 0.f;
        }
    {
        const uint16_t* mp = Mi + (wave * 16 + nl) * 136 + quad * 8;
#pragma unroll
        for (int ks = 0; ks < 4; ks++) {
            half8 m = *(const half8*)(mp + ks * 32);
            accO[0] = MFMA16H(A2[0][ks], m, accO[0], 0, 0, 0);
            accO[1] = MFMA16H(A2[1][ks], m, accO[1], 0, 0, 0);
        }
    }
#pragma unroll
    for (int mt = 0; mt < 2; mt++)
#pragma unroll
        for (int r = 0; r < 4; r++) {
            int o = mt * 16 + quad * 4 + r;
            if (o < Oz)
                out[((size_t)b * Oz + o) * Lz + t0 + wave * 16 + nl] = accO[mt][r];
        }
}

// ---------------------------------------------------------------------------
extern "C" void kernel_launch(void* const* d_in, const int* in_sizes, int n_in,
                              void* d_out, int out_size, void* d_ws, size_t ws_size,
                              hipStream_t stream) {
    const int*   tok      = (const int*)d_in[0];
    const int*   gin      = (const int*)d_in[1];
    const float* table    = (const float*)d_in[2];
    const float* w_causal = (const float*)d_in[3];
    const float* b_causal = (const float*)d_in[4];
    const float* w_f      = (const float*)d_in[5];
    const float* b_f      = (const float*)d_in[6];
    const float* w_g      = (const float*)d_in[7];
    const float* b_g      = (const float*)d_in[8];
    const float* wl_f     = (const float*)d_in[9];
    const float* bl_f     = (const float*)d_in[10];
    const float* wl_g     = (const float*)d_in[11];
    const float* bl_g     = (const float*)d_in[12];
    const float* w_res    = (const float*)d_in[13];
    const float* b_res    = (const float*)d_in[14];
    const float* w_fin1   = (const float*)d_in[15];
    const float* b_fin1   = (const float*)d_in[16];
    const float* w_fin2   = (const float*)d_in[17];
    const float* b_fin2   = (const float*)d_in[18];
    float* out = (float*)d_out;

    const size_t NRES = (size_t)Bz * Lz * Cz;        // 8388608 elements
    uint16_t* u16 = (uint16_t*)d_ws;
    uint16_t* resA = u16;                             // fp16 trunk buffers
    uint16_t* resB = resA + NRES;
    uint16_t* resC = resB + NRES;
    uint16_t* WB   = resC + NRES;                     // 147456
    uint16_t* WrB  = WB + N_WB;                       // 36864
    uint16_t* W1B  = WrB + N_WR;                      // 8192
    uint16_t* W2B  = W1B + N_W1;                      // 4096
    uint16_t* WLB  = W2B + N_W2;                      // 1179648
    uint16_t* embG = WLB + N_WLB;                     // 65536
    float* hhT     = (float*)(embG + N_EMB);          // 73728 floats
    float* proj0   = hhT + 73728;                     // 1920
    float* proj1   = proj0 + N_PROJ;                  // 1920
    float* biasrow = proj1 + N_PROJ;                  // 1152

    int npack = N_WB + N_WR + N_W1 + N_W2 + N_PROJ + N_WLB + N_EMB + N_BIAS;
    pack_k<<<(npack + 255) / 256, 256, 0, stream>>>(
        w_f, w_g, w_res, w_fin1, w_fin2, w_causal, table, gin,
        wl_f, wl_g, b_f, b_g, bl_f, bl_g,
        WB, WrB, W1B, W2B, proj0, proj1, WLB, embG, biasrow);
    hgemm_k<<<72, 256, 0, stream>>>(WLB, embG, biasrow, hhT);

    // layers 0..4 fused + inline init: writes resA (init) and resB (post-L4)
    fused_k<<<dim3(Lz / 128, Bz), 256, 0, stream>>>(
        tok, b_causal, proj0, proj1, resA, resB, WB, WrB, hhT, b_res);
    // layers 5..6 pair-fused (d = 64, 128): resB -> resC
    pair_k<<<dim3(Lz / 128, Bz), 256, 0, stream>>>(resB, resC, WB, WrB, hhT, b_res);
    // layer 7 (d = 256): C -> B
    layer_k<<<dim3(Lz / 64, Bz), 256, 0, stream>>>(
        resC, resB, WB + (size_t)7 * 16384, WrB + (size_t)7 * 4096, hhT, b_res, 7, 256);
    // layer 8 (d = 512) + head fused: reads res0 = resA, res7 = resB
    final8_k<<<dim3(Lz / 64, Bz), 256, 0, stream>>>(
        resA, resB, WB + (size_t)8 * 16384, WrB + (size_t)8 * 4096, hhT, b_res,
        W1B, W2B, b_fin1, b_fin2, out);
}